// Round 16
// baseline (290.390 us; speedup 1.0000x reference)
//
#include <hip/hip_runtime.h>
#include <hip/hip_bf16.h>

// PoolAggregator: out[b,h] = mean_s relu( W @ features[idx[b,s]] + bias )
// B=10000, S=32, N=100000, D_IN=512, D_H=512.
//
// Pipeline (ws >= 205.7 MB):
//   0) cvt_bf16: feat f32 -> featb bf16 (padded to 100352 rows), W -> Wb bf16.
//      ~87% of HBM peak (measured).
//   1) gemm_hb3: H = relu(featb @ Wb^T + b) -> bf16, m97 structure, spill-free
//      (R14-verified: 2-base-pointer staging, no row clamp, bounds(256,4)).
//      ~870 TF = the documented ceiling of this structure.
//   2) pool_mean8: out[b,:] = mean_s H[idx[b,s],:]. 8 nodes/block, 32
//      threads/node, 2x16B loads per row per thread (2x memory-level
//      parallelism vs pool_mean4, half the blocks).
// Fallbacks: ws >= 102.4 MB -> f32-reg-staged gemm; else fused gather GEMM.

#define S_NB 32
#define D_IN 512
#define D_H  512
#define BM   128
#define BN   128
#define BK   64
#define NK   (D_IN / BK)            // 8
#define NNODE 100000
#define NPAD  100352                // 784 * 128
#define NBATCH 10000
#define NTILE_N 4
#define NTILE_M 784                 // NTILES = 8 * 392, 392 % 4 == 0
#define NTILES  (NTILE_N * NTILE_M) // 3136

typedef __attribute__((ext_vector_type(8))) short  short8;
typedef __attribute__((ext_vector_type(4))) float  f32x4;
typedef __attribute__((ext_vector_type(4))) unsigned short us4;
typedef __attribute__((ext_vector_type(8))) unsigned short us8;

__device__ __forceinline__ unsigned short f2bf(float x) {
  union { float f; unsigned u; } v; v.f = x;
  unsigned r = v.u + 0x7FFFu + ((v.u >> 16) & 1u);
  return (unsigned short)(r >> 16);
}

__device__ __forceinline__ float bf2f(unsigned short x) {
  union { unsigned u; float f; } v; v.u = ((unsigned)x) << 16;
  return v.f;
}

// byte offset into a [128][64]-bf16 LDS tile (row stride 128B) with XOR swizzle
__device__ __forceinline__ int swz(int row, int cb) {
  return row * 128 + (cb ^ ((row & 7) << 4));
}

// async global->LDS, 16B/lane; LDS dest wave-uniform base + lane*16
__device__ __forceinline__ void gld_lds16(const void* g, void* l) {
  __builtin_amdgcn_global_load_lds(
      (const __attribute__((address_space(1))) unsigned int*)g,
      (__attribute__((address_space(3))) unsigned int*)l, 16, 0, 0);
}

// ---------------- Phase 0: f32 -> bf16 streaming conversion ----------------
__global__ __launch_bounds__(256, 8)
void cvt_bf16(const float* __restrict__ src, unsigned short* __restrict__ dst, int n8) {
  int i = blockIdx.x * blockDim.x + threadIdx.x;
  const int stride = gridDim.x * blockDim.x;
  for (; i < n8; i += stride) {
    f32x4 a = *(const f32x4*)(src + (size_t)i * 8);
    f32x4 b = *(const f32x4*)(src + (size_t)i * 8 + 4);
    us8 o;
    o[0] = f2bf(a.x); o[1] = f2bf(a.y); o[2] = f2bf(a.z); o[3] = f2bf(a.w);
    o[4] = f2bf(b.x); o[5] = f2bf(b.y); o[6] = f2bf(b.z); o[7] = f2bf(b.w);
    *(us8*)(dst + (size_t)i * 8) = o;
  }
}

// ---------------- Phase 1: H = relu(featb @ Wb^T + b), m97, spill-free ----------------
__global__ __launch_bounds__(256, 4)
void gemm_hb3(const unsigned short* __restrict__ featb,
              const unsigned short* __restrict__ Wb,
              const float* __restrict__ bias,
              unsigned short* __restrict__ Hb) {
  const int tid  = threadIdx.x;
  const int lane = tid & 63;
  const int wid  = tid >> 6;
  const int wr   = wid >> 1;
  const int wc   = wid & 1;

  // XCD-chunked swizzle: XCD k (bid%8) gets 392 sequential tiles, n-tile fastest.
  const int bid  = blockIdx.x;
  const int tile = (bid & 7) * (NTILES / 8) + (bid >> 3);
  const int n0   = (tile & 3) * BN;
  const int m0   = (tile >> 2) * BM;

  __shared__ __align__(16) unsigned short smem[BM * BK * 2];  // 32 KB
  unsigned short* As = smem;
  unsigned short* Bs = smem + BM * BK;

  // staging: wave w covers rows [32w, 32w+32); inst i handles rows 32w+8i..+7.
  // rl&7 == lane>>3 for ALL i -> 2 base pointers + immediate offsets.
  const int rlb = wid * 32 + (lane >> 3);
  const int g   = (lane & 7) ^ (lane >> 3);
  const unsigned short* sA = featb + (size_t)(m0 + rlb) * D_IN + g * 8;  // padded, no clamp
  const unsigned short* sB = Wb    + (size_t)(n0 + rlb) * D_IN + g * 8;
  unsigned short* dA = As + (wid * 32) * 64;
  unsigned short* dB = Bs + (wid * 32) * 64;

  f32x4 acc[4][4];
#pragma unroll
  for (int i = 0; i < 4; ++i)
#pragma unroll
    for (int j = 0; j < 4; ++j)
      acc[i][j] = (f32x4){0.f, 0.f, 0.f, 0.f};

  const int frow = lane & 15;
  const int kcb  = (lane >> 4) * 16;
  const int arow = wr * 64 + frow;
  const int brow = wc * 64 + frow;

  for (int ki = 0; ki < NK; ++ki) {
    const int k0 = ki * BK;
    if (ki) __syncthreads();            // WAR: previous tile's readers done
#pragma unroll
    for (int i = 0; i < 4; ++i) {
      gld_lds16(sA + k0 + i * 4096, dA + i * 512);
      gld_lds16(sB + k0 + i * 4096, dB + i * 512);
    }
    __syncthreads();                    // RAW: staged data visible

#pragma unroll
    for (int kk = 0; kk < 2; ++kk) {
      short8 af[4], bfr[4];
#pragma unroll
      for (int mi = 0; mi < 4; ++mi)
        af[mi] = *(const short8*)((const char*)As + swz(arow + mi * 16, kk * 64 + kcb));
#pragma unroll
      for (int ni = 0; ni < 4; ++ni)
        bfr[ni] = *(const short8*)((const char*)Bs + swz(brow + ni * 16, kk * 64 + kcb));
#pragma unroll
      for (int mi = 0; mi < 4; ++mi)
#pragma unroll
        for (int ni = 0; ni < 4; ++ni)
          acc[mi][ni] = __builtin_amdgcn_mfma_f32_16x16x32_bf16(af[mi], bfr[ni], acc[mi][ni], 0, 0, 0);
    }
  }

  // ---- Epilogue: bias+ReLU -> bf16 via XOR-swizzled LDS overlay ----
  __syncthreads();
  unsigned short* Cs = smem;            // 128x128 ushort = 32 KB overlay
  const int rq = lane >> 4;
#pragma unroll
  for (int ni = 0; ni < 4; ++ni) {
    int col = wc * 64 + ni * 16 + frow;
    float bv = bias[n0 + col];
#pragma unroll
    for (int mi = 0; mi < 4; ++mi) {
#pragma unroll
      for (int r = 0; r < 4; ++r) {
        int row = wr * 64 + mi * 16 + rq * 4 + r;
        int byt = row * 256 + ((col * 2) ^ ((row & 7) << 4));
        *(unsigned short*)((char*)Cs + byt) = f2bf(fmaxf(acc[mi][ni][r] + bv, 0.f));
      }
    }
  }
  __syncthreads();

  const int scol = (tid & 15) * 8;
#pragma unroll
  for (int it = 0; it < 8; ++it) {
    int row  = it * 16 + (tid >> 4);
    int grow = m0 + row;
    int byt  = row * 256 + (((tid & 15) * 16) ^ ((row & 7) << 4));
    us8 v = *(const us8*)((const char*)Cs + byt);
    if (grow < NNODE)
      *(us8*)(Hb + (size_t)grow * D_H + n0 + scol) = v;
  }
}

// ---------------- Phase 2: out[b,:] = mean_s H[idx[b,s],:] ----------------
// 8 nodes/block, 32 threads/node, 2x16B loads per row (2x MLP vs pool_mean4).
__global__ __launch_bounds__(256, 8)
void pool_mean8(const unsigned short* __restrict__ Hb,
                const int* __restrict__ nidx,
                float* __restrict__ out) {
  const int b8 = blockIdx.x;            // group of 8 output nodes
  const int q  = threadIdx.x >> 5;      // node in group 0..7
  const int t  = threadIdx.x & 31;      // thread within node
  const int b  = b8 * 8 + q;

  __shared__ int rows[8][S_NB];
  rows[threadIdx.x >> 5][threadIdx.x & 31] = nidx[b8 * 8 * S_NB + threadIdx.x];
  __syncthreads();

  const int c = t * 16;                 // 16 cols per thread (2 x 16B loads)
  float s[16];
#pragma unroll
  for (int j = 0; j < 16; ++j) s[j] = 0.f;

#pragma unroll
  for (int sIt = 0; sIt < S_NB; ++sIt) {
    const unsigned short* rp = Hb + (size_t)rows[q][sIt] * D_H + c;
    us8 v0 = *(const us8*)(rp);
    us8 v1 = *(const us8*)(rp + 8);
#pragma unroll
    for (int j = 0; j < 8; ++j) { s[j] += bf2f(v0[j]); s[8 + j] += bf2f(v1[j]); }
  }

  const float inv = 1.0f / (float)S_NB;
  float* op = out + (size_t)b * D_H + c;
#pragma unroll
  for (int v = 0; v < 4; ++v) {
    f32x4 o; o.x = s[v*4] * inv; o.y = s[v*4+1] * inv;
    o.z = s[v*4+2] * inv; o.w = s[v*4+3] * inv;
    *(f32x4*)(op + v * 4) = o;
  }
}

// ---------------- Fallback A: f32 reg-staged GEMM ----------------
__global__ __launch_bounds__(256, 4)
void gemm_h(const float* __restrict__ feat,
            const float* __restrict__ Wm,
            const float* __restrict__ bias,
            unsigned short* __restrict__ Hb) {
  const int tid  = threadIdx.x;
  const int lane = tid & 63;
  const int wid  = tid >> 6;
  const int wr   = wid >> 1;
  const int wc   = wid & 1;
  const int n0   = blockIdx.x * BN;
  const int m0   = blockIdx.y * BM;

  __shared__ __align__(16) unsigned short As[BM * 64];
  __shared__ __align__(16) unsigned short Bs[BM * 64];

  const int lr = tid >> 4;
  const int lc = tid & 15;

  const float* aptr[8];
  const float* wptr[8];
#pragma unroll
  for (int p = 0; p < 8; ++p) {
    int row = p * 16 + lr;
    int gr  = m0 + row; if (gr > NNODE - 1) gr = NNODE - 1;
    aptr[p] = feat + (size_t)gr * D_IN + lc * 4;
    wptr[p] = Wm + (size_t)(n0 + row) * D_IN + lc * 4;
  }

  f32x4 acc[4][4];
#pragma unroll
  for (int i = 0; i < 4; ++i)
#pragma unroll
    for (int j = 0; j < 4; ++j)
      acc[i][j] = (f32x4){0.f, 0.f, 0.f, 0.f};

  const int frow = lane & 15;
  const int kcb  = (lane >> 4) * 16;
  const int arow = wr * 64 + frow;
  const int brow = wc * 64 + frow;

  for (int k0 = 0; k0 < D_IN; k0 += 64) {
    __syncthreads();
#pragma unroll
    for (int p = 0; p < 8; ++p) {
      int row = p * 16 + lr;
      f32x4 av = *(const f32x4*)(aptr[p] + k0);
      f32x4 wv = *(const f32x4*)(wptr[p] + k0);
      us4 a4, w4;
      a4.x = f2bf(av.x); a4.y = f2bf(av.y); a4.z = f2bf(av.z); a4.w = f2bf(av.w);
      w4.x = f2bf(wv.x); w4.y = f2bf(wv.y); w4.z = f2bf(wv.z); w4.w = f2bf(wv.w);
      *(us4*)((char*)As + swz(row, lc * 8)) = a4;
      *(us4*)((char*)Bs + swz(row, lc * 8)) = w4;
    }
    __syncthreads();

#pragma unroll
    for (int kk = 0; kk < 2; ++kk) {
      short8 af[4], bfr[4];
#pragma unroll
      for (int mi = 0; mi < 4; ++mi)
        af[mi] = *(const short8*)((const char*)As + swz(arow + mi * 16, kk * 64 + kcb));
#pragma unroll
      for (int ni = 0; ni < 4; ++ni)
        bfr[ni] = *(const short8*)((const char*)Bs + swz(brow + ni * 16, kk * 64 + kcb));
#pragma unroll
      for (int mi = 0; mi < 4; ++mi)
#pragma unroll
        for (int ni = 0; ni < 4; ++ni)
          acc[mi][ni] = __builtin_amdgcn_mfma_f32_16x16x32_bf16(af[mi], bfr[ni], acc[mi][ni], 0, 0, 0);
    }
  }

  const int rq = lane >> 4;
#pragma unroll
  for (int ni = 0; ni < 4; ++ni) {
    int col = n0 + wc * 64 + ni * 16 + frow;
    float bv = bias[col];
#pragma unroll
    for (int mi = 0; mi < 4; ++mi) {
#pragma unroll
      for (int r = 0; r < 4; ++r) {
        int grow = m0 + wr * 64 + mi * 16 + rq * 4 + r;
        if (grow < NNODE)
          Hb[(size_t)grow * D_H + col] = f2bf(fmaxf(acc[mi][ni][r] + bv, 0.f));
      }
    }
  }
}

// ---------------- Fallback B: fused gathered GEMM (round-1) ----------------
__global__ __launch_bounds__(256, 4)
void pool_aggr_gemm(const int* __restrict__ nidx_g,
                    const float* __restrict__ feat,
                    const float* __restrict__ Wm,
                    const float* __restrict__ bias,
                    float* __restrict__ out) {
  const int tid  = threadIdx.x;
  const int lane = tid & 63;
  const int wid  = tid >> 6;
  const int wr   = wid >> 1;
  const int wc   = wid & 1;
  const int n0   = blockIdx.x * BN;
  const int mb   = blockIdx.y;

  __shared__ __align__(16) unsigned short As[BM * 64];
  __shared__ __align__(16) unsigned short Bs[BM * 64];
  __shared__ int nid[BM];

  if (tid < BM) nid[tid] = nidx_g[mb * BM + tid];
  __syncthreads();

  const int lr = tid >> 4;
  const int lc = tid & 15;

  const float* aptr[8];
  const float* wptr[8];
#pragma unroll
  for (int p = 0; p < 8; ++p) {
    int row = p * 16 + lr;
    aptr[p] = feat + (size_t)nid[row] * D_IN + lc * 4;
    wptr[p] = Wm + (size_t)(n0 + row) * D_IN + lc * 4;
  }

  f32x4 acc[4][4];
#pragma unroll
  for (int i = 0; i < 4; ++i)
#pragma unroll
    for (int j = 0; j < 4; ++j)
      acc[i][j] = (f32x4){0.f, 0.f, 0.f, 0.f};

  const int frow = lane & 15;
  const int kcb  = (lane >> 4) * 16;
  const int arow = wr * 64 + frow;
  const int brow = wc * 64 + frow;

  for (int k0 = 0; k0 < D_IN; k0 += 64) {
    __syncthreads();
#pragma unroll
    for (int p = 0; p < 8; ++p) {
      int row = p * 16 + lr;
      f32x4 av = *(const f32x4*)(aptr[p] + k0);
      f32x4 wv = *(const f32x4*)(wptr[p] + k0);
      us4 a4, w4;
      a4.x = f2bf(av.x); a4.y = f2bf(av.y); a4.z = f2bf(av.z); a4.w = f2bf(av.w);
      w4.x = f2bf(wv.x); w4.y = f2bf(wv.y); w4.z = f2bf(wv.z); w4.w = f2bf(wv.w);
      *(us4*)((char*)As + swz(row, lc * 8)) = a4;
      *(us4*)((char*)Bs + swz(row, lc * 8)) = w4;
    }
    __syncthreads();

#pragma unroll
    for (int kk = 0; kk < 2; ++kk) {
      short8 af[4], bfr[4];
#pragma unroll
      for (int mi = 0; mi < 4; ++mi)
        af[mi] = *(const short8*)((const char*)As + swz(arow + mi * 16, kk * 64 + kcb));
#pragma unroll
      for (int ni = 0; ni < 4; ++ni)
        bfr[ni] = *(const short8*)((const char*)Bs + swz(brow + ni * 16, kk * 64 + kcb));
#pragma unroll
      for (int mi = 0; mi < 4; ++mi)
#pragma unroll
        for (int ni = 0; ni < 4; ++ni)
          acc[mi][ni] = __builtin_amdgcn_mfma_f32_16x16x32_bf16(af[mi], bfr[ni], acc[mi][ni], 0, 0, 0);
    }
  }

  const int rq = lane >> 4;
#pragma unroll
  for (int ni = 0; ni < 4; ++ni) {
    int col = n0 + wc * 64 + ni * 16 + frow;
    float bv = bias[col];
#pragma unroll
    for (int bl = 0; bl < 2; ++bl) {
      float s = 0.f;
#pragma unroll
      for (int m2 = 0; m2 < 2; ++m2) {
        int mi = bl * 2 + m2;
#pragma unroll
        for (int r = 0; r < 4; ++r)
          s += fmaxf(acc[mi][ni][r] + bv, 0.f);
      }
      s += __shfl_xor(s, 16);
      s += __shfl_xor(s, 32);
      if (rq == 0) {
        int bb = mb * 4 + wr * 2 + bl;
        out[(size_t)bb * D_H + col] = s * (1.0f / (float)S_NB);
      }
    }
  }
}

extern "C" void kernel_launch(void* const* d_in, const int* in_sizes, int n_in,
                              void* d_out, int out_size, void* d_ws, size_t ws_size,
                              hipStream_t stream) {
  const int*   nidx = (const int*)d_in[0];    // [10000,32]
  const float* feat = (const float*)d_in[1];  // [100000,512]
  const float* Wm   = (const float*)d_in[2];  // [512,512]
  const float* bias = (const float*)d_in[3];  // [512]
  float* out = (float*)d_out;                 // [10000,512]

  const size_t featb_elems = (size_t)NPAD * D_IN;
  const size_t wb_elems    = (size_t)D_H * D_IN;
  const size_t h_elems     = (size_t)NNODE * D_H;
  const size_t need = (featb_elems + wb_elems + h_elems) * sizeof(unsigned short); // ~205.7 MB
  const size_t h_bytes = h_elems * sizeof(unsigned short);

  if (ws_size >= need) {
    unsigned short* featb = (unsigned short*)d_ws;
    unsigned short* Wb    = featb + featb_elems;
    unsigned short* Hb    = Wb + wb_elems;
    cvt_bf16<<<2048, 256, 0, stream>>>(feat, featb, NNODE * D_IN / 8);
    cvt_bf16<<<128, 256, 0, stream>>>(Wm, Wb, D_H * D_IN / 8);
    gemm_hb3<<<NTILES, 256, 0, stream>>>(featb, Wb, bias, Hb);
    pool_mean8<<<NBATCH / 8, 256, 0, stream>>>(Hb, nidx, out);
  } else if (ws_size >= h_bytes) {
    unsigned short* Hb = (unsigned short*)d_ws;
    dim3 g1(D_H / BN, (NNODE + 127) / 128);
    gemm_h<<<g1, 256, 0, stream>>>(feat, Wm, bias, Hb);
    pool_mean8<<<NBATCH / 8, 256, 0, stream>>>(Hb, nidx, out);
  } else {
    dim3 grid(D_H / BN, NBATCH / 4);
    pool_aggr_gemm<<<grid, 256, 0, stream>>>(nidx, feat, Wm, bias, out);
  }
}

// Round 17
// 184.902 us; speedup vs baseline: 1.5705x; 1.5705x over previous
//
#include <hip/hip_runtime.h>
#include <hip/hip_bf16.h>

// PoolAggregator: out[b,h] = mean_s relu( W @ features[idx[b,s]] + bias )
// B=10000, S=32, N=100000, D_IN=512, D_H=512.
//
// Pipeline (ws >= 205.7 MB):
//   0) cvt_bf16: feat f32 -> featb bf16 (padded to 100352 rows), W -> Wb bf16.
//      ~87% of HBM peak (measured).
//   1) gemm_hb3: H = relu(featb @ Wb^T + b) -> bf16, m97 structure, spill-free
//      (R14-verified: 2-base-pointer staging, no row clamp, bounds(256,4)).
//   2) pool_mean8: out[b,:] = mean_s H[idx[b,s],:]. 8 nodes/block, 32
//      threads/node, 2x16B loads/row (2x MLP). R16 fix: bounds(256,4) --
//      the (256,8) 64-VGPR cap spilled the 16-float accumulator (WRITE 287MB).
// Fallbacks: ws >= 102.4 MB -> f32-reg-staged gemm; else fused gather GEMM.

#define S_NB 32
#define D_IN 512
#define D_H  512
#define BM   128
#define BN   128
#define BK   64
#define NK   (D_IN / BK)            // 8
#define NNODE 100000
#define NPAD  100352                // 784 * 128
#define NBATCH 10000
#define NTILE_N 4
#define NTILE_M 784                 // NTILES = 8 * 392, 392 % 4 == 0
#define NTILES  (NTILE_N * NTILE_M) // 3136

typedef __attribute__((ext_vector_type(8))) short  short8;
typedef __attribute__((ext_vector_type(4))) float  f32x4;
typedef __attribute__((ext_vector_type(4))) unsigned short us4;
typedef __attribute__((ext_vector_type(8))) unsigned short us8;

__device__ __forceinline__ unsigned short f2bf(float x) {
  union { float f; unsigned u; } v; v.f = x;
  unsigned r = v.u + 0x7FFFu + ((v.u >> 16) & 1u);
  return (unsigned short)(r >> 16);
}

__device__ __forceinline__ float bf2f(unsigned short x) {
  union { unsigned u; float f; } v; v.u = ((unsigned)x) << 16;
  return v.f;
}

// byte offset into a [128][64]-bf16 LDS tile (row stride 128B) with XOR swizzle
__device__ __forceinline__ int swz(int row, int cb) {
  return row * 128 + (cb ^ ((row & 7) << 4));
}

// async global->LDS, 16B/lane; LDS dest wave-uniform base + lane*16
__device__ __forceinline__ void gld_lds16(const void* g, void* l) {
  __builtin_amdgcn_global_load_lds(
      (const __attribute__((address_space(1))) unsigned int*)g,
      (__attribute__((address_space(3))) unsigned int*)l, 16, 0, 0);
}

// ---------------- Phase 0: f32 -> bf16 streaming conversion ----------------
__global__ __launch_bounds__(256, 8)
void cvt_bf16(const float* __restrict__ src, unsigned short* __restrict__ dst, int n8) {
  int i = blockIdx.x * blockDim.x + threadIdx.x;
  const int stride = gridDim.x * blockDim.x;
  for (; i < n8; i += stride) {
    f32x4 a = *(const f32x4*)(src + (size_t)i * 8);
    f32x4 b = *(const f32x4*)(src + (size_t)i * 8 + 4);
    us8 o;
    o[0] = f2bf(a.x); o[1] = f2bf(a.y); o[2] = f2bf(a.z); o[3] = f2bf(a.w);
    o[4] = f2bf(b.x); o[5] = f2bf(b.y); o[6] = f2bf(b.z); o[7] = f2bf(b.w);
    *(us8*)(dst + (size_t)i * 8) = o;
  }
}

// ---------------- Phase 1: H = relu(featb @ Wb^T + b), m97, spill-free ----------------
__global__ __launch_bounds__(256, 4)
void gemm_hb3(const unsigned short* __restrict__ featb,
              const unsigned short* __restrict__ Wb,
              const float* __restrict__ bias,
              unsigned short* __restrict__ Hb) {
  const int tid  = threadIdx.x;
  const int lane = tid & 63;
  const int wid  = tid >> 6;
  const int wr   = wid >> 1;
  const int wc   = wid & 1;

  // XCD-chunked swizzle: XCD k (bid%8) gets 392 sequential tiles, n-tile fastest.
  const int bid  = blockIdx.x;
  const int tile = (bid & 7) * (NTILES / 8) + (bid >> 3);
  const int n0   = (tile & 3) * BN;
  const int m0   = (tile >> 2) * BM;

  __shared__ __align__(16) unsigned short smem[BM * BK * 2];  // 32 KB
  unsigned short* As = smem;
  unsigned short* Bs = smem + BM * BK;

  // staging: wave w covers rows [32w, 32w+32); inst i handles rows 32w+8i..+7.
  // rl&7 == lane>>3 for ALL i -> 2 base pointers + immediate offsets.
  const int rlb = wid * 32 + (lane >> 3);
  const int g   = (lane & 7) ^ (lane >> 3);
  const unsigned short* sA = featb + (size_t)(m0 + rlb) * D_IN + g * 8;  // padded, no clamp
  const unsigned short* sB = Wb    + (size_t)(n0 + rlb) * D_IN + g * 8;
  unsigned short* dA = As + (wid * 32) * 64;
  unsigned short* dB = Bs + (wid * 32) * 64;

  f32x4 acc[4][4];
#pragma unroll
  for (int i = 0; i < 4; ++i)
#pragma unroll
    for (int j = 0; j < 4; ++j)
      acc[i][j] = (f32x4){0.f, 0.f, 0.f, 0.f};

  const int frow = lane & 15;
  const int kcb  = (lane >> 4) * 16;
  const int arow = wr * 64 + frow;
  const int brow = wc * 64 + frow;

  for (int ki = 0; ki < NK; ++ki) {
    const int k0 = ki * BK;
    if (ki) __syncthreads();            // WAR: previous tile's readers done
#pragma unroll
    for (int i = 0; i < 4; ++i) {
      gld_lds16(sA + k0 + i * 4096, dA + i * 512);
      gld_lds16(sB + k0 + i * 4096, dB + i * 512);
    }
    __syncthreads();                    // RAW: staged data visible

#pragma unroll
    for (int kk = 0; kk < 2; ++kk) {
      short8 af[4], bfr[4];
#pragma unroll
      for (int mi = 0; mi < 4; ++mi)
        af[mi] = *(const short8*)((const char*)As + swz(arow + mi * 16, kk * 64 + kcb));
#pragma unroll
      for (int ni = 0; ni < 4; ++ni)
        bfr[ni] = *(const short8*)((const char*)Bs + swz(brow + ni * 16, kk * 64 + kcb));
#pragma unroll
      for (int mi = 0; mi < 4; ++mi)
#pragma unroll
        for (int ni = 0; ni < 4; ++ni)
          acc[mi][ni] = __builtin_amdgcn_mfma_f32_16x16x32_bf16(af[mi], bfr[ni], acc[mi][ni], 0, 0, 0);
    }
  }

  // ---- Epilogue: bias+ReLU -> bf16 via XOR-swizzled LDS overlay ----
  __syncthreads();
  unsigned short* Cs = smem;            // 128x128 ushort = 32 KB overlay
  const int rq = lane >> 4;
#pragma unroll
  for (int ni = 0; ni < 4; ++ni) {
    int col = wc * 64 + ni * 16 + frow;
    float bv = bias[n0 + col];
#pragma unroll
    for (int mi = 0; mi < 4; ++mi) {
#pragma unroll
      for (int r = 0; r < 4; ++r) {
        int row = wr * 64 + mi * 16 + rq * 4 + r;
        int byt = row * 256 + ((col * 2) ^ ((row & 7) << 4));
        *(unsigned short*)((char*)Cs + byt) = f2bf(fmaxf(acc[mi][ni][r] + bv, 0.f));
      }
    }
  }
  __syncthreads();

  const int scol = (tid & 15) * 8;
#pragma unroll
  for (int it = 0; it < 8; ++it) {
    int row  = it * 16 + (tid >> 4);
    int grow = m0 + row;
    int byt  = row * 256 + (((tid & 15) * 16) ^ ((row & 7) << 4));
    us8 v = *(const us8*)((const char*)Cs + byt);
    if (grow < NNODE)
      *(us8*)(Hb + (size_t)grow * D_H + n0 + scol) = v;
  }
}

// ---------------- Phase 2: out[b,:] = mean_s H[idx[b,s],:] ----------------
// 8 nodes/block, 32 threads/node, 2x16B loads per row. bounds(256,4): 128-VGPR
// cap so the 16-float accumulator stays in registers (R16: (256,8) spilled it).
__global__ __launch_bounds__(256, 4)
void pool_mean8(const unsigned short* __restrict__ Hb,
                const int* __restrict__ nidx,
                float* __restrict__ out) {
  const int b8 = blockIdx.x;            // group of 8 output nodes
  const int q  = threadIdx.x >> 5;      // node in group 0..7
  const int t  = threadIdx.x & 31;      // thread within node
  const int b  = b8 * 8 + q;

  __shared__ int rows[8][S_NB];
  rows[threadIdx.x >> 5][threadIdx.x & 31] = nidx[b8 * 8 * S_NB + threadIdx.x];
  __syncthreads();

  const int c = t * 16;                 // 16 cols per thread (2 x 16B loads)
  float s[16];
#pragma unroll
  for (int j = 0; j < 16; ++j) s[j] = 0.f;

#pragma unroll
  for (int sIt = 0; sIt < S_NB; ++sIt) {
    const unsigned short* rp = Hb + (size_t)rows[q][sIt] * D_H + c;
    us8 v0 = *(const us8*)(rp);
    us8 v1 = *(const us8*)(rp + 8);
#pragma unroll
    for (int j = 0; j < 8; ++j) { s[j] += bf2f(v0[j]); s[8 + j] += bf2f(v1[j]); }
  }

  const float inv = 1.0f / (float)S_NB;
  float* op = out + (size_t)b * D_H + c;
#pragma unroll
  for (int v = 0; v < 4; ++v) {
    f32x4 o; o.x = s[v*4] * inv; o.y = s[v*4+1] * inv;
    o.z = s[v*4+2] * inv; o.w = s[v*4+3] * inv;
    *(f32x4*)(op + v * 4) = o;
  }
}

// ---------------- Fallback A: f32 reg-staged GEMM ----------------
__global__ __launch_bounds__(256, 4)
void gemm_h(const float* __restrict__ feat,
            const float* __restrict__ Wm,
            const float* __restrict__ bias,
            unsigned short* __restrict__ Hb) {
  const int tid  = threadIdx.x;
  const int lane = tid & 63;
  const int wid  = tid >> 6;
  const int wr   = wid >> 1;
  const int wc   = wid & 1;
  const int n0   = blockIdx.x * BN;
  const int m0   = blockIdx.y * BM;

  __shared__ __align__(16) unsigned short As[BM * 64];
  __shared__ __align__(16) unsigned short Bs[BM * 64];

  const int lr = tid >> 4;
  const int lc = tid & 15;

  const float* aptr[8];
  const float* wptr[8];
#pragma unroll
  for (int p = 0; p < 8; ++p) {
    int row = p * 16 + lr;
    int gr  = m0 + row; if (gr > NNODE - 1) gr = NNODE - 1;
    aptr[p] = feat + (size_t)gr * D_IN + lc * 4;
    wptr[p] = Wm + (size_t)(n0 + row) * D_IN + lc * 4;
  }

  f32x4 acc[4][4];
#pragma unroll
  for (int i = 0; i < 4; ++i)
#pragma unroll
    for (int j = 0; j < 4; ++j)
      acc[i][j] = (f32x4){0.f, 0.f, 0.f, 0.f};

  const int frow = lane & 15;
  const int kcb  = (lane >> 4) * 16;
  const int arow = wr * 64 + frow;
  const int brow = wc * 64 + frow;

  for (int k0 = 0; k0 < D_IN; k0 += 64) {
    __syncthreads();
#pragma unroll
    for (int p = 0; p < 8; ++p) {
      int row = p * 16 + lr;
      f32x4 av = *(const f32x4*)(aptr[p] + k0);
      f32x4 wv = *(const f32x4*)(wptr[p] + k0);
      us4 a4, w4;
      a4.x = f2bf(av.x); a4.y = f2bf(av.y); a4.z = f2bf(av.z); a4.w = f2bf(av.w);
      w4.x = f2bf(wv.x); w4.y = f2bf(wv.y); w4.z = f2bf(wv.z); w4.w = f2bf(wv.w);
      *(us4*)((char*)As + swz(row, lc * 8)) = a4;
      *(us4*)((char*)Bs + swz(row, lc * 8)) = w4;
    }
    __syncthreads();

#pragma unroll
    for (int kk = 0; kk < 2; ++kk) {
      short8 af[4], bfr[4];
#pragma unroll
      for (int mi = 0; mi < 4; ++mi)
        af[mi] = *(const short8*)((const char*)As + swz(arow + mi * 16, kk * 64 + kcb));
#pragma unroll
      for (int ni = 0; ni < 4; ++ni)
        bfr[ni] = *(const short8*)((const char*)Bs + swz(brow + ni * 16, kk * 64 + kcb));
#pragma unroll
      for (int mi = 0; mi < 4; ++mi)
#pragma unroll
        for (int ni = 0; ni < 4; ++ni)
          acc[mi][ni] = __builtin_amdgcn_mfma_f32_16x16x32_bf16(af[mi], bfr[ni], acc[mi][ni], 0, 0, 0);
    }
  }

  const int rq = lane >> 4;
#pragma unroll
  for (int ni = 0; ni < 4; ++ni) {
    int col = n0 + wc * 64 + ni * 16 + frow;
    float bv = bias[col];
#pragma unroll
    for (int mi = 0; mi < 4; ++mi) {
#pragma unroll
      for (int r = 0; r < 4; ++r) {
        int grow = m0 + wr * 64 + mi * 16 + rq * 4 + r;
        if (grow < NNODE)
          Hb[(size_t)grow * D_H + col] = f2bf(fmaxf(acc[mi][ni][r] + bv, 0.f));
      }
    }
  }
}

// ---------------- Fallback B: fused gathered GEMM (round-1) ----------------
__global__ __launch_bounds__(256, 4)
void pool_aggr_gemm(const int* __restrict__ nidx_g,
                    const float* __restrict__ feat,
                    const float* __restrict__ Wm,
                    const float* __restrict__ bias,
                    float* __restrict__ out) {
  const int tid  = threadIdx.x;
  const int lane = tid & 63;
  const int wid  = tid >> 6;
  const int wr   = wid >> 1;
  const int wc   = wid & 1;
  const int n0   = blockIdx.x * BN;
  const int mb   = blockIdx.y;

  __shared__ __align__(16) unsigned short As[BM * 64];
  __shared__ __align__(16) unsigned short Bs[BM * 64];
  __shared__ int nid[BM];

  if (tid < BM) nid[tid] = nidx_g[mb * BM + tid];
  __syncthreads();

  const int lr = tid >> 4;
  const int lc = tid & 15;

  const float* aptr[8];
  const float* wptr[8];
#pragma unroll
  for (int p = 0; p < 8; ++p) {
    int row = p * 16 + lr;
    aptr[p] = feat + (size_t)nid[row] * D_IN + lc * 4;
    wptr[p] = Wm + (size_t)(n0 + row) * D_IN + lc * 4;
  }

  f32x4 acc[4][4];
#pragma unroll
  for (int i = 0; i < 4; ++i)
#pragma unroll
    for (int j = 0; j < 4; ++j)
      acc[i][j] = (f32x4){0.f, 0.f, 0.f, 0.f};

  const int frow = lane & 15;
  const int kcb  = (lane >> 4) * 16;
  const int arow = wr * 64 + frow;
  const int brow = wc * 64 + frow;

  for (int k0 = 0; k0 < D_IN; k0 += 64) {
    __syncthreads();
#pragma unroll
    for (int p = 0; p < 8; ++p) {
      int row = p * 16 + lr;
      f32x4 av = *(const f32x4*)(aptr[p] + k0);
      f32x4 wv = *(const f32x4*)(wptr[p] + k0);
      us4 a4, w4;
      a4.x = f2bf(av.x); a4.y = f2bf(av.y); a4.z = f2bf(av.z); a4.w = f2bf(av.w);
      w4.x = f2bf(wv.x); w4.y = f2bf(wv.y); w4.z = f2bf(wv.z); w4.w = f2bf(wv.w);
      *(us4*)((char*)As + swz(row, lc * 8)) = a4;
      *(us4*)((char*)Bs + swz(row, lc * 8)) = w4;
    }
    __syncthreads();

#pragma unroll
    for (int kk = 0; kk < 2; ++kk) {
      short8 af[4], bfr[4];
#pragma unroll
      for (int mi = 0; mi < 4; ++mi)
        af[mi] = *(const short8*)((const char*)As + swz(arow + mi * 16, kk * 64 + kcb));
#pragma unroll
      for (int ni = 0; ni < 4; ++ni)
        bfr[ni] = *(const short8*)((const char*)Bs + swz(brow + ni * 16, kk * 64 + kcb));
#pragma unroll
      for (int mi = 0; mi < 4; ++mi)
#pragma unroll
        for (int ni = 0; ni < 4; ++ni)
          acc[mi][ni] = __builtin_amdgcn_mfma_f32_16x16x32_bf16(af[mi], bfr[ni], acc[mi][ni], 0, 0, 0);
    }
  }

  const int rq = lane >> 4;
#pragma unroll
  for (int ni = 0; ni < 4; ++ni) {
    int col = n0 + wc * 64 + ni * 16 + frow;
    float bv = bias[col];
#pragma unroll
    for (int bl = 0; bl < 2; ++bl) {
      float s = 0.f;
#pragma unroll
      for (int m2 = 0; m2 < 2; ++m2) {
        int mi = bl * 2 + m2;
#pragma unroll
        for (int r = 0; r < 4; ++r)
          s += fmaxf(acc[mi][ni][r] + bv, 0.f);
      }
      s += __shfl_xor(s, 16);
      s += __shfl_xor(s, 32);
      if (rq == 0) {
        int bb = mb * 4 + wr * 2 + bl;
        out[(size_t)bb * D_H + col] = s * (1.0f / (float)S_NB);
      }
    }
  }
}

extern "C" void kernel_launch(void* const* d_in, const int* in_sizes, int n_in,
                              void* d_out, int out_size, void* d_ws, size_t ws_size,
                              hipStream_t stream) {
  const int*   nidx = (const int*)d_in[0];    // [10000,32]
  const float* feat = (const float*)d_in[1];  // [100000,512]
  const float* Wm   = (const float*)d_in[2];  // [512,512]
  const float* bias = (const float*)d_in[3];  // [512]
  float* out = (float*)d_out;                 // [10000,512]

  const size_t featb_elems = (size_t)NPAD * D_IN;
  const size_t wb_elems    = (size_t)D_H * D_IN;
  const size_t h_elems     = (size_t)NNODE * D_H;
  const size_t need = (featb_elems + wb_elems + h_elems) * sizeof(unsigned short); // ~205.7 MB
  const size_t h_bytes = h_elems * sizeof(unsigned short);

  if (ws_size >= need) {
    unsigned short* featb = (unsigned short*)d_ws;
    unsigned short* Wb    = featb + featb_elems;
    unsigned short* Hb    = Wb + wb_elems;
    cvt_bf16<<<2048, 256, 0, stream>>>(feat, featb, NNODE * D_IN / 8);
    cvt_bf16<<<128, 256, 0, stream>>>(Wm, Wb, D_H * D_IN / 8);
    gemm_hb3<<<NTILES, 256, 0, stream>>>(featb, Wb, bias, Hb);
    pool_mean8<<<NBATCH / 8, 256, 0, stream>>>(Hb, nidx, out);
  } else if (ws_size >= h_bytes) {
    unsigned short* Hb = (unsigned short*)d_ws;
    dim3 g1(D_H / BN, (NNODE + 127) / 128);
    gemm_h<<<g1, 256, 0, stream>>>(feat, Wm, bias, Hb);
    pool_mean8<<<NBATCH / 8, 256, 0, stream>>>(Hb, nidx, out);
  } else {
    dim3 grid(D_H / BN, NBATCH / 4);
    pool_aggr_gemm<<<grid, 256, 0, stream>>>(nidx, feat, Wm, bias, out);
  }
}